// Round 14
// baseline (118.030 us; speedup 1.0000x reference)
//
#include <hip/hip_runtime.h>

// ShuffleNet unit, NCHW. B=64, Cin=Cout=480, mid=120, H=W=28, G=3.
// prep: BN fold + fragment-direct split-bf16 weight packing.
// K1: conv1 MFMA; conflict-free (ch-pair,px4) staging; single-bf16 x.
// K2: dw3x3+BN+shuffle on bf16 tmp1 -> packed bf16 tmp2 [b][cs][hw] (no G).
// K3: conv3 MFMA; B staged from tmp2 into 8KB LDS fragments; direct per-lane
//     dword x-read/out-write epilogue (no osr transpose, 1 barrier).

namespace {
constexpr int CIN = 480;
constexpr int MID = 120;
constexpr int HWP = 784;
constexpr float EPSV = 1e-5f;

constexpr size_t TMP1_N = (size_t)64 * MID * HWP;   // bf16 slots (12.04 MB)
constexpr int WA1_N = 3 * 3 * 5 * 64 * 8;           // 23040 shorts
constexpr int WA3_N = 3 * 10 * 2 * 64 * 8;          // 30720 shorts

constexpr int S1W = 84;    // K1 x-tile stride in u32 words
constexpr int S1O = 65;    // K1 epilogue transpose stride (floats)
constexpr int S2O = 69;    // K2 dout stride (floats)
}

typedef short bf16x8 __attribute__((ext_vector_type(8)));
typedef float f32x4  __attribute__((ext_vector_type(4)));

__device__ inline unsigned short f2bf(float v) {
    unsigned u = __float_as_uint(v);
    return (unsigned short)((u + 0x7fffu + ((u >> 16) & 1u)) >> 16);
}
__device__ inline float bf2f(unsigned s) {
    return __uint_as_float(s << 16);
}
__device__ inline void split2(float v, unsigned short& h, unsigned short& l) {
    h = f2bf(v);
    l = f2bf(v - bf2f((unsigned)h));
}

// ---------------- prep: BN fold + weight frag-packing ----------------
__global__ __launch_bounds__(256) void prep_k(
    const float* __restrict__ w1, const float* __restrict__ w3,
    const float* __restrict__ g1, const float* __restrict__ b1,
    const float* __restrict__ m1, const float* __restrict__ v1,
    const float* __restrict__ g2, const float* __restrict__ b2,
    const float* __restrict__ m2, const float* __restrict__ v2,
    const float* __restrict__ g3, const float* __restrict__ b3,
    const float* __restrict__ m3, const float* __restrict__ v3,
    float* __restrict__ par, unsigned short* __restrict__ wpk)
{
    const int t = blockIdx.x * 256 + threadIdx.x;
    if (t < 720) {
        if (t < 120) {
            const float s = g1[t] * rsqrtf(v1[t] + EPSV);
            par[t] = s; par[120 + t] = fmaf(-m1[t], s, b1[t]);
        } else if (t < 240) {
            const int c = t - 120;
            const float s = g2[c] * rsqrtf(v2[c] + EPSV);
            par[240 + c] = s; par[360 + c] = fmaf(-m2[c], s, b2[c]);
        } else {
            const int c = t - 240;
            const float s = g3[c] * rsqrtf(v3[c] + EPSV);
            par[480 + c] = s; par[960 + c] = fmaf(-m3[c], s, b3[c]);
        }
    } else if (t < 3600) {
        // w1 frags: [g][mt<3][ks<5][lane] -> 8 hi + 8 lo bf16
        const int t1   = t - 720;
        const int lane = t1 & 63;
        const int rest = t1 >> 6;
        const int ks   = rest % 5;
        const int mtg  = rest / 5;
        const int mt   = mtg % 3;
        const int g    = mtg / 3;
        const int row  = mt * 16 + (lane & 15);
        const int k0   = ks * 32 + (lane >> 4) * 8;
        unsigned short h[8], l[8];
#pragma unroll
        for (int j = 0; j < 8; ++j) {
            float v = (row < 40) ? w1[(size_t)(g * 40 + row) * 160 + k0 + j] : 0.f;
            split2(v, h[j], l[j]);
        }
        *reinterpret_cast<uint4*>(wpk + (size_t)t1 * 8)         = *reinterpret_cast<uint4*>(h);
        *reinterpret_cast<uint4*>(wpk + WA1_N + (size_t)t1 * 8) = *reinterpret_cast<uint4*>(l);
    } else if (t < 7440) {
        // w3 frags: [g][mt<10][ks<2][lane]; k >= 40 zero-padded
        const int t3   = t - 3600;
        const int lane = t3 & 63;
        const int rest = t3 >> 6;
        const int ks   = rest % 2;
        const int mtg  = rest / 2;
        const int mt   = mtg % 10;
        const int g    = mtg / 10;
        const int row  = mt * 16 + (lane & 15);
        const int k0   = ks * 32 + (lane >> 4) * 8;
        unsigned short h[8], l[8];
#pragma unroll
        for (int j = 0; j < 8; ++j) {
            const int k = k0 + j;
            float v = (k < 40) ? w3[(size_t)(g * 160 + row) * 40 + k] : 0.f;
            split2(v, h[j], l[j]);
        }
        *reinterpret_cast<uint4*>(wpk + 2 * WA1_N + (size_t)t3 * 8)         = *reinterpret_cast<uint4*>(h);
        *reinterpret_cast<uint4*>(wpk + 2 * WA1_N + WA3_N + (size_t)t3 * 8) = *reinterpret_cast<uint4*>(l);
    }
}

// ---------------- K1: conv1 (480->120, G=3) + BN + ReLU, MFMA ----------------
// grid (784, 3), block 256 = 4 waves; 64-px tile, M=48(pad), K=160.
__global__ __launch_bounds__(256) void k1_mfma(
    const float* __restrict__ x, const unsigned short* __restrict__ wA1h,
    const float* __restrict__ par, unsigned short* __restrict__ tmp1)
{
    __shared__ __align__(16) unsigned xs32[64 * S1W];   // [px][84] u32 = 2 bf16 ch
    __shared__ float sL[40], shL[40];

    const int tid  = threadIdx.x;
    const int lane = tid & 63;
    const int wv   = tid >> 6;
    const int g    = blockIdx.y;
    const int p0   = blockIdx.x * 64;

    if (tid < 40) { sL[tid] = par[g * 40 + tid]; shL[tid] = par[120 + g * 40 + tid]; }

    // staging: 80 ch-pairs x 16 px4; px4 fixed per thread, cp = (tid&15)+16i
    const int px4s = (tid >> 4) & 15;
    {
        const int ps = p0 + px4s * 4;
        const int bs = ps / HWP;
        const int hws = ps - bs * HWP;
        const float* __restrict__ xb = x + ((size_t)bs * CIN + g * 160) * HWP + hws;

        float4 v0[5], v1[5];
#pragma unroll
        for (int i = 0; i < 5; ++i) {
            const int cp = (tid & 15) + 16 * i;
            v0[i] = *reinterpret_cast<const float4*>(xb + (size_t)(2 * cp)     * HWP);
            v1[i] = *reinterpret_cast<const float4*>(xb + (size_t)(2 * cp + 1) * HWP);
        }
#pragma unroll
        for (int i = 0; i < 5; ++i) {
            const int cp = (tid & 15) + 16 * i;
            unsigned* d = xs32 + (px4s * 4) * S1W + cp;
            d[0]       = (unsigned)f2bf(v0[i].x) | ((unsigned)f2bf(v1[i].x) << 16);
            d[S1W]     = (unsigned)f2bf(v0[i].y) | ((unsigned)f2bf(v1[i].y) << 16);
            d[2 * S1W] = (unsigned)f2bf(v0[i].z) | ((unsigned)f2bf(v1[i].z) << 16);
            d[3 * S1W] = (unsigned)f2bf(v0[i].w) | ((unsigned)f2bf(v1[i].w) << 16);
        }
    }
    __syncthreads();

    const unsigned short* __restrict__ wA1l = wA1h + WA1_N;
    const unsigned short* xsh = reinterpret_cast<const unsigned short*>(xs32);
    f32x4 acc[3];
#pragma unroll
    for (int mt = 0; mt < 3; ++mt) acc[mt] = f32x4{0.f, 0.f, 0.f, 0.f};

    const int n16 = lane & 15;
    const int kq  = lane >> 4;
    const int pxl = wv * 16 + n16;
#pragma unroll
    for (int ks = 0; ks < 5; ++ks) {
        const bf16x8 Bv = *reinterpret_cast<const bf16x8*>(
            xsh + pxl * (2 * S1W) + ks * 32 + kq * 8);
#pragma unroll
        for (int mt = 0; mt < 3; ++mt) {
            const size_t fi = (((size_t)(g * 3 + mt) * 5 + ks) * 64 + lane) * 8;
            const bf16x8 Ah = *reinterpret_cast<const bf16x8*>(wA1h + fi);
            const bf16x8 Al = *reinterpret_cast<const bf16x8*>(wA1l + fi);
            acc[mt] = __builtin_amdgcn_mfma_f32_16x16x32_bf16(Ah, Bv, acc[mt], 0, 0, 0);
            acc[mt] = __builtin_amdgcn_mfma_f32_16x16x32_bf16(Al, Bv, acc[mt], 0, 0, 0);
        }
    }
    __syncthreads();                       // xs reads done; safe to reuse

    // epilogue A: BN + ReLU -> LDS transpose (reuse xs32 as float area)
    float* osr = reinterpret_cast<float*>(xs32);
    {
#pragma unroll
        for (int mt = 0; mt < 3; ++mt) {
#pragma unroll
            for (int r = 0; r < 4; ++r) {
                const int ocl = mt * 16 + kq * 4 + r;
                if (ocl < 40) {
                    float val = fmaf(acc[mt][r], sL[ocl], shL[ocl]);
                    osr[ocl * S1O + pxl] = val > 0.f ? val : 0.f;
                }
            }
        }
    }
    __syncthreads();

    // epilogue B: 40 ocl x 16 px4 = 640 tasks -> 8B bf16 stores
#pragma unroll
    for (int i = 0; i < 3; ++i) {
        const int task = tid + i * 256;
        if (task < 640) {
            const int ocl = task >> 4;
            const int px4 = task & 15;
            const int p   = p0 + px4 * 4;
            const int b   = p / HWP;
            const int hw  = p - b * HWP;
            const float* s = osr + ocl * S1O + px4 * 4;
            const unsigned lo = (unsigned)f2bf(s[0]) | ((unsigned)f2bf(s[1]) << 16);
            const unsigned hi = (unsigned)f2bf(s[2]) | ((unsigned)f2bf(s[3]) << 16);
            *reinterpret_cast<uint2*>(
                tmp1 + ((size_t)b * MID + g * 40 + ocl) * HWP + hw) = make_uint2(lo, hi);
        }
    }
}

// ---------------- K2: dw3x3 + BN + shuffle -> packed bf16 tmp2 [b][cs][hw] ----------------
// grid (784), block 256. Tile = 64 px x all 120 ch.
__global__ __launch_bounds__(256) void k2_dw(
    const unsigned short* __restrict__ tmp1, const float* __restrict__ w2,
    const float* __restrict__ par, unsigned short* __restrict__ tmp2)
{
    __shared__ float dout[MID * S2O];       // [shuffled ch][px]
    __shared__ float w2s[1080];
    __shared__ float s2s[120], sh2s[120];

    const int tid = threadIdx.x;
    const int bx  = blockIdx.x;
    const int p0  = bx * 64;

    for (int i = tid; i < 1080; i += 256) w2s[i] = w2[i];
    if (tid < 120) { s2s[tid] = par[240 + tid]; sh2s[tid] = par[360 + tid]; }
    __syncthreads();

    // phase A: stencil, 120 ch x 16 px4 = 1920 tasks
#pragma unroll
    for (int i = 0; i < 8; ++i) {
        const int task = tid + i * 256;
        if (task < 1920) {
            const int ch  = task >> 4;
            const int px4 = task & 15;
            const int p   = p0 + px4 * 4;
            const int b   = p / HWP;
            const int hw  = p - b * HWP;
            const int h   = hw / 28, w = hw - h * 28;
            const unsigned short* __restrict__ in = tmp1 + ((size_t)b * MID + ch) * HWP;
            const float* wk = w2s + ch * 9;

            float a0 = 0.f, a1 = 0.f, a2 = 0.f, a3 = 0.f;
#pragma unroll
            for (int dh = -1; dh <= 1; ++dh) {
                const int hh = h + dh;
                if (hh < 0 || hh > 27) continue;
                const unsigned short* r = in + hh * 28 + w;
                const uint2 cc = *reinterpret_cast<const uint2*>(r);
                const float c0 = bf2f(cc.x & 0xffffu), c1 = bf2f(cc.x >> 16);
                const float c2 = bf2f(cc.y & 0xffffu), c3 = bf2f(cc.y >> 16);
                const float cl = (w > 0)  ? bf2f(r[-1]) : 0.f;
                const float cr = (w < 24) ? bf2f(r[4])  : 0.f;
                const float* wr = wk + (dh + 1) * 3;
                a0 = fmaf(cl, wr[0], a0); a0 = fmaf(c0, wr[1], a0); a0 = fmaf(c1, wr[2], a0);
                a1 = fmaf(c0, wr[0], a1); a1 = fmaf(c1, wr[1], a1); a1 = fmaf(c2, wr[2], a1);
                a2 = fmaf(c1, wr[0], a2); a2 = fmaf(c2, wr[1], a2); a2 = fmaf(c3, wr[2], a2);
                a3 = fmaf(c2, wr[0], a3); a3 = fmaf(c3, wr[1], a3); a3 = fmaf(cr, wr[2], a3);
            }
            const float s  = s2s[ch];
            const float sh = sh2s[ch];
            const int gi = ch / 40;
            const int cs = (ch - gi * 40) * 3 + gi;        // channel shuffle
            float* d = dout + cs * S2O + px4 * 4;
            d[0] = fmaf(a0, s, sh); d[1] = fmaf(a1, s, sh);
            d[2] = fmaf(a2, s, sh); d[3] = fmaf(a3, s, sh);
        }
    }
    __syncthreads();

    // phase B: 120 cs x 8 px8 = 960 tasks -> 16B contiguous bf16 stores
    // (HWP = 784 is divisible by 8, so 8-aligned runs never straddle batches)
#pragma unroll
    for (int i = 0; i < 4; ++i) {
        const int task = tid + i * 256;
        if (task < 960) {
            const int cs  = task >> 3;
            const int px8 = task & 7;
            const int p   = p0 + px8 * 8;
            const int b   = p / HWP;
            const int hw  = p - b * HWP;
            const float* dr = dout + cs * S2O + px8 * 8;
            uint4 o;
            o.x = (unsigned)f2bf(dr[0]) | ((unsigned)f2bf(dr[1]) << 16);
            o.y = (unsigned)f2bf(dr[2]) | ((unsigned)f2bf(dr[3]) << 16);
            o.z = (unsigned)f2bf(dr[4]) | ((unsigned)f2bf(dr[5]) << 16);
            o.w = (unsigned)f2bf(dr[6]) | ((unsigned)f2bf(dr[7]) << 16);
            *reinterpret_cast<uint4*>(
                tmp2 + ((size_t)b * MID + cs) * HWP + hw) = o;
        }
    }
}

// ---------------- K3: conv3 (120->480) + BN + ReLU + shortcut, MFMA ----------------
// grid (784, 3): gk = shuffled group, M=160 (10 mt), 64-px tile, K=40 pad 64.
// B staged from tmp2 into 8KB LDS fragments; direct dword x-read/out-write.
__global__ __launch_bounds__(256) void k3_mfma(
    const unsigned short* __restrict__ tmp2, const unsigned short* __restrict__ wA3h,
    const float* __restrict__ par,
    const float* __restrict__ x, float* __restrict__ out)
{
    __shared__ __align__(16) unsigned short Bfr[4096];   // [kb8<8][nt4][n16][8]
    __shared__ float sL[160], shL[160];

    const int tid  = threadIdx.x;
    const int lane = tid & 63;
    const int wv   = tid >> 6;
    const int bx   = blockIdx.x;
    const int gk   = blockIdx.y;
    const int p0   = bx * 64;

    if (tid < 160) {
        sL[tid]  = par[480 + gk * 160 + tid];
        shL[tid] = par[960 + gk * 160 + tid];
    }
    // zero k-pads: kb8 = 5..7 -> shorts [2560, 4096) = 192 uint4
    if (tid < 192)
        *reinterpret_cast<uint4*>(Bfr + 2560 + tid * 8) = make_uint4(0u, 0u, 0u, 0u);

    // ---- B-stage: 40 csl x 16 px4 = 640 tasks (uint2 loads, b16 scatter) ----
#pragma unroll
    for (int i = 0; i < 3; ++i) {
        const int task = tid + i * 256;
        if (task < 640) {
            const int csl = task >> 4;
            const int px4 = task & 15;
            const int p   = p0 + px4 * 4;
            const int b   = p / HWP;
            const int hw  = p - b * HWP;
            const uint2 cc = *reinterpret_cast<const uint2*>(
                tmp2 + ((size_t)b * MID + gk * 40 + csl) * HWP + hw);
            const int kb8 = csl >> 3, j = csl & 7;
            unsigned short vals[4] = {
                (unsigned short)(cc.x & 0xffffu), (unsigned short)(cc.x >> 16),
                (unsigned short)(cc.y & 0xffffu), (unsigned short)(cc.y >> 16) };
#pragma unroll
            for (int pp = 0; pp < 4; ++pp) {
                const int px  = px4 * 4 + pp;
                const int nt  = px >> 4, n16 = px & 15;
                Bfr[((kb8 * 4 + nt) * 16 + n16) * 8 + j] = vals[pp];
            }
        }
    }

    // ---- x-shortcut prefetch (direct per-lane dwords, issued pre-barrier) ----
    const int n16 = lane & 15, kq = lane >> 4;
    const int pxl = wv * 16 + n16;
    const int pg  = p0 + pxl;
    const int bg  = pg / HWP;
    const int hwg = pg - bg * HWP;
    const size_t xbase = (size_t)bg * CIN * HWP + hwg;
    float xv[10][4];
#pragma unroll
    for (int mt = 0; mt < 10; ++mt) {
#pragma unroll
        for (int r = 0; r < 4; ++r) {
            const int oc = gk * 160 + mt * 16 + kq * 4 + r;
            xv[mt][r] = x[xbase + (size_t)oc * HWP];
        }
    }
    __syncthreads();

    // ---- MFMA: 2 ks x 10 mt x 2 passes ----
    const unsigned short* __restrict__ wA3l = wA3h + WA3_N;
    f32x4 acc[10];
#pragma unroll
    for (int mt = 0; mt < 10; ++mt) acc[mt] = f32x4{0.f, 0.f, 0.f, 0.f};

#pragma unroll
    for (int ks = 0; ks < 2; ++ks) {
        const int kb8 = ks * 4 + kq;
        const bf16x8 Bv = *reinterpret_cast<const bf16x8*>(
            Bfr + ((kb8 * 4 + wv) * 16 + n16) * 8);
#pragma unroll
        for (int mt = 0; mt < 10; ++mt) {
            const size_t fi = (((size_t)(gk * 10 + mt) * 2 + ks) * 64 + lane) * 8;
            const bf16x8 Ah = *reinterpret_cast<const bf16x8*>(wA3h + fi);
            const bf16x8 Al = *reinterpret_cast<const bf16x8*>(wA3l + fi);
            acc[mt] = __builtin_amdgcn_mfma_f32_16x16x32_bf16(Ah, Bv, acc[mt], 0, 0, 0);
            acc[mt] = __builtin_amdgcn_mfma_f32_16x16x32_bf16(Al, Bv, acc[mt], 0, 0, 0);
        }
    }

    // ---- epilogue: BN + ReLU + shortcut, direct dword stores ----
#pragma unroll
    for (int mt = 0; mt < 10; ++mt) {
#pragma unroll
        for (int r = 0; r < 4; ++r) {
            const int ocl = mt * 16 + kq * 4 + r;
            const int oc  = gk * 160 + ocl;
            float val = fmaf(acc[mt][r], sL[ocl], shL[ocl]);
            val = val > 0.f ? val : 0.f;
            out[xbase + (size_t)oc * HWP] = val + xv[mt][r];
        }
    }
}

extern "C" void kernel_launch(void* const* d_in, const int* in_sizes, int n_in,
                              void* d_out, int out_size, void* d_ws, size_t ws_size,
                              hipStream_t stream) {
    const float* x  = (const float*)d_in[0];
    const float* w1 = (const float*)d_in[1];
    const float* g1 = (const float*)d_in[2];
    const float* b1 = (const float*)d_in[3];
    const float* m1 = (const float*)d_in[4];
    const float* v1 = (const float*)d_in[5];
    const float* w2 = (const float*)d_in[6];
    const float* g2 = (const float*)d_in[7];
    const float* b2 = (const float*)d_in[8];
    const float* m2 = (const float*)d_in[9];
    const float* v2 = (const float*)d_in[10];
    const float* w3 = (const float*)d_in[11];
    const float* g3 = (const float*)d_in[12];
    const float* b3 = (const float*)d_in[13];
    const float* m3 = (const float*)d_in[14];
    const float* v3 = (const float*)d_in[15];
    float* out = (float*)d_out;

    unsigned short* tmp1 = (unsigned short*)d_ws;         // 12.04 MB
    unsigned short* tmp2 = tmp1 + TMP1_N;                 // 12.04 MB
    float* par = (float*)(tmp2 + TMP1_N);                 // 1440 floats
    unsigned short* wpk = (unsigned short*)(par + 1440);  // 215 KB

    prep_k<<<30, 256, 0, stream>>>(w1, w3, g1, b1, m1, v1, g2, b2, m2, v2,
                                   g3, b3, m3, v3, par, wpk);
    k1_mfma<<<dim3(784, 3), 256, 0, stream>>>(x, wpk, par, tmp1);
    k2_dw  <<<784,          256, 0, stream>>>(tmp1, w2, par, tmp2);
    k3_mfma<<<dim3(784, 3), 256, 0, stream>>>(tmp2, wpk + 2 * WA1_N, par, x, out);
}

// Round 15
// 99.112 us; speedup vs baseline: 1.1909x; 1.1909x over previous
//
#include <hip/hip_runtime.h>

// ShuffleNet unit, NCHW. B=64, Cin=Cout=480, mid=120, H=W=28, G=3.
// Best-known recombination (round-10 structure):
// prep: BN fold + fragment-direct split-bf16 weight packing.
// K1: conv1 MFMA; conflict-free (ch-pair,px4) staging; single-bf16 x in LDS.
// K2: dw3x3+BN+shuffle on bf16 tmp1 -> G fragment buffer (+ pad zeros).
// K3: conv3 MFMA, B direct from G (no staging); osr LDS transpose epilogue,
//     float4 x-read/out-write. No T14 prefetch (VGPR pressure hurt).

namespace {
constexpr int CIN = 480;
constexpr int MID = 120;
constexpr int HWP = 784;
constexpr float EPSV = 1e-5f;

constexpr size_t TMP1_N   = (size_t)64 * MID * HWP;           // element slots
constexpr size_t G_SHORTS = (size_t)784 * 3 * 4096;
constexpr size_t G_FLOATS = G_SHORTS / 2;
constexpr size_t PAR_OFF  = TMP1_N + G_FLOATS;                // float offset
constexpr int WA1_N = 3 * 3 * 5 * 64 * 8;                     // 23040 shorts
constexpr int WA3_N = 3 * 10 * 2 * 64 * 8;                    // 30720 shorts

constexpr int S1W = 84;    // K1 x-tile stride in u32 words (16B-aligned frags)
constexpr int S1O = 65;    // K1 epilogue transpose stride (floats)
constexpr int S2O = 69;    // K2 out LDS stride
constexpr int S3O = 67;    // K3 out LDS stride
}

typedef short bf16x8 __attribute__((ext_vector_type(8)));
typedef float f32x4  __attribute__((ext_vector_type(4)));

__device__ inline unsigned short f2bf(float v) {
    unsigned u = __float_as_uint(v);
    return (unsigned short)((u + 0x7fffu + ((u >> 16) & 1u)) >> 16);
}
__device__ inline float bf2f(unsigned s) {
    return __uint_as_float(s << 16);
}
__device__ inline void split2(float v, unsigned short& h, unsigned short& l) {
    h = f2bf(v);
    l = f2bf(v - bf2f((unsigned)h));
}

// ---------------- prep: BN fold + weight frag-packing ----------------
__global__ __launch_bounds__(256) void prep_k(
    const float* __restrict__ w1, const float* __restrict__ w3,
    const float* __restrict__ g1, const float* __restrict__ b1,
    const float* __restrict__ m1, const float* __restrict__ v1,
    const float* __restrict__ g2, const float* __restrict__ b2,
    const float* __restrict__ m2, const float* __restrict__ v2,
    const float* __restrict__ g3, const float* __restrict__ b3,
    const float* __restrict__ m3, const float* __restrict__ v3,
    float* __restrict__ par, unsigned short* __restrict__ wpk)
{
    const int t = blockIdx.x * 256 + threadIdx.x;
    if (t < 720) {
        if (t < 120) {
            const float s = g1[t] * rsqrtf(v1[t] + EPSV);
            par[t] = s; par[120 + t] = fmaf(-m1[t], s, b1[t]);
        } else if (t < 240) {
            const int c = t - 120;
            const float s = g2[c] * rsqrtf(v2[c] + EPSV);
            par[240 + c] = s; par[360 + c] = fmaf(-m2[c], s, b2[c]);
        } else {
            const int c = t - 240;
            const float s = g3[c] * rsqrtf(v3[c] + EPSV);
            par[480 + c] = s; par[960 + c] = fmaf(-m3[c], s, b3[c]);
        }
    } else if (t < 3600) {
        // w1 frags: [g][mt<3][ks<5][lane] -> 8 hi + 8 lo bf16
        const int t1   = t - 720;
        const int lane = t1 & 63;
        const int rest = t1 >> 6;
        const int ks   = rest % 5;
        const int mtg  = rest / 5;
        const int mt   = mtg % 3;
        const int g    = mtg / 3;
        const int row  = mt * 16 + (lane & 15);
        const int k0   = ks * 32 + (lane >> 4) * 8;
        unsigned short h[8], l[8];
#pragma unroll
        for (int j = 0; j < 8; ++j) {
            float v = (row < 40) ? w1[(size_t)(g * 40 + row) * 160 + k0 + j] : 0.f;
            split2(v, h[j], l[j]);
        }
        *reinterpret_cast<uint4*>(wpk + (size_t)t1 * 8)         = *reinterpret_cast<uint4*>(h);
        *reinterpret_cast<uint4*>(wpk + WA1_N + (size_t)t1 * 8) = *reinterpret_cast<uint4*>(l);
    } else if (t < 7440) {
        // w3 frags: [g][mt<10][ks<2][lane]; k >= 40 zero-padded
        const int t3   = t - 3600;
        const int lane = t3 & 63;
        const int rest = t3 >> 6;
        const int ks   = rest % 2;
        const int mtg  = rest / 2;
        const int mt   = mtg % 10;
        const int g    = mtg / 10;
        const int row  = mt * 16 + (lane & 15);
        const int k0   = ks * 32 + (lane >> 4) * 8;
        unsigned short h[8], l[8];
#pragma unroll
        for (int j = 0; j < 8; ++j) {
            const int k = k0 + j;
            float v = (k < 40) ? w3[(size_t)(g * 160 + row) * 40 + k] : 0.f;
            split2(v, h[j], l[j]);
        }
        *reinterpret_cast<uint4*>(wpk + 2 * WA1_N + (size_t)t3 * 8)         = *reinterpret_cast<uint4*>(h);
        *reinterpret_cast<uint4*>(wpk + 2 * WA1_N + WA3_N + (size_t)t3 * 8) = *reinterpret_cast<uint4*>(l);
    }
}

// ---------------- K1: conv1 (480->120, G=3) + BN + ReLU, MFMA ----------------
// grid (784, 3), block 256 = 4 waves; 64-px tile, M=48(pad), K=160.
// staging: (ch-pair in lane-low, px4 in lane-high) -> conflict-free LDS writes.
__global__ __launch_bounds__(256) void k1_mfma(
    const float* __restrict__ x, const unsigned short* __restrict__ wA1h,
    const float* __restrict__ par, unsigned short* __restrict__ tmp1)
{
    __shared__ __align__(16) unsigned xs32[64 * S1W];   // [px][84] u32 = 2 bf16 ch
    __shared__ float sL[40], shL[40];

    const int tid  = threadIdx.x;
    const int lane = tid & 63;
    const int wv   = tid >> 6;
    const int g    = blockIdx.y;
    const int p0   = blockIdx.x * 64;

    if (tid < 40) { sL[tid] = par[g * 40 + tid]; shL[tid] = par[120 + g * 40 + tid]; }

    // ---- staging: 80 ch-pairs x 16 px4; px4 fixed per thread, cp = (tid&15)+16i ----
    const int px4s = (tid >> 4) & 15;
    {
        const int ps = p0 + px4s * 4;
        const int bs = ps / HWP;
        const int hws = ps - bs * HWP;
        const float* __restrict__ xb = x + ((size_t)bs * CIN + g * 160) * HWP + hws;

        float4 v0[5], v1[5];
#pragma unroll
        for (int i = 0; i < 5; ++i) {
            const int cp = (tid & 15) + 16 * i;
            v0[i] = *reinterpret_cast<const float4*>(xb + (size_t)(2 * cp)     * HWP);
            v1[i] = *reinterpret_cast<const float4*>(xb + (size_t)(2 * cp + 1) * HWP);
        }
#pragma unroll
        for (int i = 0; i < 5; ++i) {
            const int cp = (tid & 15) + 16 * i;
            unsigned* d = xs32 + (px4s * 4) * S1W + cp;
            d[0]       = (unsigned)f2bf(v0[i].x) | ((unsigned)f2bf(v1[i].x) << 16);
            d[S1W]     = (unsigned)f2bf(v0[i].y) | ((unsigned)f2bf(v1[i].y) << 16);
            d[2 * S1W] = (unsigned)f2bf(v0[i].z) | ((unsigned)f2bf(v1[i].z) << 16);
            d[3 * S1W] = (unsigned)f2bf(v0[i].w) | ((unsigned)f2bf(v1[i].w) << 16);
        }
    }
    __syncthreads();

    const unsigned short* __restrict__ wA1l = wA1h + WA1_N;
    const unsigned short* xsh = reinterpret_cast<const unsigned short*>(xs32);
    f32x4 acc[3];
#pragma unroll
    for (int mt = 0; mt < 3; ++mt) acc[mt] = f32x4{0.f, 0.f, 0.f, 0.f};

    const int n16 = lane & 15;
    const int kq  = lane >> 4;
    const int pxl = wv * 16 + n16;
#pragma unroll
    for (int ks = 0; ks < 5; ++ks) {
        const bf16x8 Bv = *reinterpret_cast<const bf16x8*>(
            xsh + pxl * (2 * S1W) + ks * 32 + kq * 8);
#pragma unroll
        for (int mt = 0; mt < 3; ++mt) {
            const size_t fi = (((size_t)(g * 3 + mt) * 5 + ks) * 64 + lane) * 8;
            const bf16x8 Ah = *reinterpret_cast<const bf16x8*>(wA1h + fi);
            const bf16x8 Al = *reinterpret_cast<const bf16x8*>(wA1l + fi);
            acc[mt] = __builtin_amdgcn_mfma_f32_16x16x32_bf16(Ah, Bv, acc[mt], 0, 0, 0);
            acc[mt] = __builtin_amdgcn_mfma_f32_16x16x32_bf16(Al, Bv, acc[mt], 0, 0, 0);
        }
    }
    __syncthreads();                       // xs reads done; safe to reuse

    // epilogue A: BN + ReLU -> LDS transpose (reuse xs32 as float area)
    float* osr = reinterpret_cast<float*>(xs32);
    {
#pragma unroll
        for (int mt = 0; mt < 3; ++mt) {
#pragma unroll
            for (int r = 0; r < 4; ++r) {
                const int ocl = mt * 16 + kq * 4 + r;
                if (ocl < 40) {
                    float val = fmaf(acc[mt][r], sL[ocl], shL[ocl]);
                    osr[ocl * S1O + pxl] = val > 0.f ? val : 0.f;
                }
            }
        }
    }
    __syncthreads();

    // epilogue B: 40 ocl x 16 px4 = 640 tasks -> 8B bf16 stores
#pragma unroll
    for (int i = 0; i < 3; ++i) {
        const int task = tid + i * 256;
        if (task < 640) {
            const int ocl = task >> 4;
            const int px4 = task & 15;
            const int p   = p0 + px4 * 4;
            const int b   = p / HWP;
            const int hw  = p - b * HWP;
            const float* s = osr + ocl * S1O + px4 * 4;
            const unsigned lo = (unsigned)f2bf(s[0]) | ((unsigned)f2bf(s[1]) << 16);
            const unsigned hi = (unsigned)f2bf(s[2]) | ((unsigned)f2bf(s[3]) << 16);
            *reinterpret_cast<uint2*>(
                tmp1 + ((size_t)b * MID + g * 40 + ocl) * HWP + hw) = make_uint2(lo, hi);
        }
    }
}

// ---------------- K2: dw3x3 + BN + shuffle -> bf16 G fragments + pad zeros ----------------
// grid (784), block 256. Tile = 64 px x all 120 ch.
__global__ __launch_bounds__(256) void k2_dw(
    const unsigned short* __restrict__ tmp1, const float* __restrict__ w2,
    const float* __restrict__ par, unsigned short* __restrict__ G)
{
    __shared__ float dout[MID * S2O];       // [shuffled ch][px]
    __shared__ float w2s[1080];
    __shared__ float s2s[120], sh2s[120];

    const int tid = threadIdx.x;
    const int bx  = blockIdx.x;
    const int p0  = bx * 64;

    // G pad zero-fill for this bx: 3 groups x 1536 shorts = 576 uint4 tasks
#pragma unroll
    for (int i = 0; i < 3; ++i) {
        const int task = tid + i * 256;
        if (task < 576) {
            const int gk  = task / 192;
            const int off = task - gk * 192;
            *reinterpret_cast<uint4*>(G + ((size_t)bx * 3 + gk) * 4096 + 2560 + (size_t)off * 8) =
                make_uint4(0u, 0u, 0u, 0u);
        }
    }

    for (int i = tid; i < 1080; i += 256) w2s[i] = w2[i];
    if (tid < 120) { s2s[tid] = par[240 + tid]; sh2s[tid] = par[360 + tid]; }
    __syncthreads();

    // phase A: stencil, 120 ch x 16 px4 = 1920 tasks
#pragma unroll
    for (int i = 0; i < 8; ++i) {
        const int task = tid + i * 256;
        if (task < 1920) {
            const int ch  = task >> 4;
            const int px4 = task & 15;
            const int p   = p0 + px4 * 4;
            const int b   = p / HWP;
            const int hw  = p - b * HWP;
            const int h   = hw / 28, w = hw - h * 28;
            const unsigned short* __restrict__ in = tmp1 + ((size_t)b * MID + ch) * HWP;
            const float* wk = w2s + ch * 9;

            float a0 = 0.f, a1 = 0.f, a2 = 0.f, a3 = 0.f;
#pragma unroll
            for (int dh = -1; dh <= 1; ++dh) {
                const int hh = h + dh;
                if (hh < 0 || hh > 27) continue;
                const unsigned short* r = in + hh * 28 + w;
                const uint2 cc = *reinterpret_cast<const uint2*>(r);
                const float c0 = bf2f(cc.x & 0xffffu), c1 = bf2f(cc.x >> 16);
                const float c2 = bf2f(cc.y & 0xffffu), c3 = bf2f(cc.y >> 16);
                const float cl = (w > 0)  ? bf2f(r[-1]) : 0.f;
                const float cr = (w < 24) ? bf2f(r[4])  : 0.f;
                const float* wr = wk + (dh + 1) * 3;
                a0 = fmaf(cl, wr[0], a0); a0 = fmaf(c0, wr[1], a0); a0 = fmaf(c1, wr[2], a0);
                a1 = fmaf(c0, wr[0], a1); a1 = fmaf(c1, wr[1], a1); a1 = fmaf(c2, wr[2], a1);
                a2 = fmaf(c1, wr[0], a2); a2 = fmaf(c2, wr[1], a2); a2 = fmaf(c3, wr[2], a2);
                a3 = fmaf(c2, wr[0], a3); a3 = fmaf(c3, wr[1], a3); a3 = fmaf(cr, wr[2], a3);
            }
            const float s  = s2s[ch];
            const float sh = sh2s[ch];
            const int gi = ch / 40;
            const int cs = (ch - gi * 40) * 3 + gi;        // channel shuffle
            float* d = dout + cs * S2O + px4 * 4;
            d[0] = fmaf(a0, s, sh); d[1] = fmaf(a1, s, sh);
            d[2] = fmaf(a2, s, sh); d[3] = fmaf(a3, s, sh);
        }
    }
    __syncthreads();

    // phase B: pack 8 shuffled ch x 1 px -> 16B G store. 15 cb x 64 px = 960 tasks
#pragma unroll
    for (int i = 0; i < 4; ++i) {
        const int task = tid + i * 256;
        if (task < 960) {
            const int cb  = task >> 6;
            const int pxl = task & 63;
            const int cs0 = cb * 8;
            unsigned short res[8];
#pragma unroll
            for (int j = 0; j < 8; ++j)
                res[j] = f2bf(dout[(cs0 + j) * S2O + pxl]);
            const int gk  = cs0 / 40;
            const int icg = cs0 - gk * 40;
            const int kb8 = icg >> 3, ks = kb8 >> 2, kbl = kb8 & 3;
            const int nt  = pxl >> 4, n16 = pxl & 15;
            unsigned short* dst = G +
                (((((size_t)bx * 3 + gk) * 2 + ks) * 4 + kbl) * 4 + nt) * 128 + n16 * 8;
            *reinterpret_cast<uint4*>(dst) = *reinterpret_cast<uint4*>(res);
        }
    }
}

// ---------------- K3: conv3 (120->480) + BN + ReLU + shortcut, MFMA ----------------
// grid (784, 6): g = by>>1, mh = by&1 (M=80). B direct from G; LDS-transposed epilogue.
__global__ __launch_bounds__(256) void k3_mfma(
    const unsigned short* __restrict__ G, const unsigned short* __restrict__ wA3h,
    const float* __restrict__ par,
    const float* __restrict__ x, float* __restrict__ out)
{
    __shared__ float osr[80 * S3O];
    __shared__ float sL[80], shL[80];

    const int tid  = threadIdx.x;
    const int lane = tid & 63;
    const int wv   = tid >> 6;
    const int bx   = blockIdx.x;
    const int g    = blockIdx.y >> 1;
    const int mh   = blockIdx.y & 1;
    if (tid < 80) {
        sL[tid]  = par[480 + g * 160 + mh * 80 + tid];
        shL[tid] = par[960 + g * 160 + mh * 80 + tid];
    }
    __syncthreads();

    const unsigned short* __restrict__ wA3l = wA3h + WA3_N;
    const int nt = wv;
    f32x4 acc[5];
#pragma unroll
    for (int mt = 0; mt < 5; ++mt) acc[mt] = f32x4{0.f, 0.f, 0.f, 0.f};

    const int kbl = lane >> 4, n16l = lane & 15;
#pragma unroll
    for (int ks = 0; ks < 2; ++ks) {
        const bf16x8 Bv = *reinterpret_cast<const bf16x8*>(
            G + (((((size_t)bx * 3 + g) * 2 + ks) * 4 + kbl) * 4 + nt) * 128 + n16l * 8);
#pragma unroll
        for (int mt = 0; mt < 5; ++mt) {
            const size_t fi = (((size_t)(g * 10 + mh * 5 + mt) * 2 + ks) * 64 + lane) * 8;
            const bf16x8 Ah = *reinterpret_cast<const bf16x8*>(wA3h + fi);
            const bf16x8 Al = *reinterpret_cast<const bf16x8*>(wA3l + fi);
            acc[mt] = __builtin_amdgcn_mfma_f32_16x16x32_bf16(Ah, Bv, acc[mt], 0, 0, 0);
            acc[mt] = __builtin_amdgcn_mfma_f32_16x16x32_bf16(Al, Bv, acc[mt], 0, 0, 0);
        }
    }

    // epilogue A: BN + ReLU -> LDS transpose
    {
        const int n16 = lane & 15, kq = lane >> 4;
        const int pxl = nt * 16 + n16;
#pragma unroll
        for (int mt = 0; mt < 5; ++mt) {
#pragma unroll
            for (int r = 0; r < 4; ++r) {
                const int ocl = mt * 16 + kq * 4 + r;
                float val = fmaf(acc[mt][r], sL[ocl], shL[ocl]);
                osr[ocl * S3O + pxl] = val > 0.f ? val : 0.f;
            }
        }
    }
    __syncthreads();

    // epilogue B: float4 shortcut-read + out-write. 80 ocl x 16 px4 = 1280 tasks
#pragma unroll
    for (int i = 0; i < 5; ++i) {
        const int task = tid + i * 256;
        const int ocl  = task >> 4;
        const int px4  = task & 15;
        const int p    = bx * 64 + px4 * 4;
        const int b    = p / HWP;
        const int hw   = p - b * HWP;
        const int oc   = g * 160 + mh * 80 + ocl;
        const size_t idx = ((size_t)b * CIN + oc) * HWP + hw;
        const float* s = osr + ocl * S3O + px4 * 4;
        const float4 sc = *reinterpret_cast<const float4*>(x + idx);
        float4 o;
        o.x = s[0] + sc.x; o.y = s[1] + sc.y;
        o.z = s[2] + sc.z; o.w = s[3] + sc.w;
        *reinterpret_cast<float4*>(out + idx) = o;
    }
}

extern "C" void kernel_launch(void* const* d_in, const int* in_sizes, int n_in,
                              void* d_out, int out_size, void* d_ws, size_t ws_size,
                              hipStream_t stream) {
    const float* x  = (const float*)d_in[0];
    const float* w1 = (const float*)d_in[1];
    const float* g1 = (const float*)d_in[2];
    const float* b1 = (const float*)d_in[3];
    const float* m1 = (const float*)d_in[4];
    const float* v1 = (const float*)d_in[5];
    const float* w2 = (const float*)d_in[6];
    const float* g2 = (const float*)d_in[7];
    const float* b2 = (const float*)d_in[8];
    const float* m2 = (const float*)d_in[9];
    const float* v2 = (const float*)d_in[10];
    const float* w3 = (const float*)d_in[11];
    const float* g3 = (const float*)d_in[12];
    const float* b3 = (const float*)d_in[13];
    const float* m3 = (const float*)d_in[14];
    const float* v3 = (const float*)d_in[15];
    float* out = (float*)d_out;

    float* wsf = (float*)d_ws;
    unsigned short* tmp1 = (unsigned short*)wsf;                  // 12.04 MB used
    unsigned short* G = (unsigned short*)(wsf + TMP1_N);          // 19.27 MB
    float* par = wsf + PAR_OFF;                                   // 1440 floats
    unsigned short* wpk = (unsigned short*)(par + 1440);          // 215 KB

    prep_k<<<30, 256, 0, stream>>>(w1, w3, g1, b1, m1, v1, g2, b2, m2, v2,
                                   g3, b3, m3, v3, par, wpk);
    k1_mfma<<<dim3(784, 3), 256, 0, stream>>>(x, wpk, par, tmp1);
    k2_dw  <<<784,          256, 0, stream>>>(tmp1, w2, par, G);
    k3_mfma<<<dim3(784, 6), 256, 0, stream>>>(G, wpk + 2 * WA1_N, par, x, out);
}